// Round 3
// baseline (669.534 us; speedup 1.0000x reference)
//
#include <hip/hip_runtime.h>

// ---------------------------------------------------------------------------
// MambaBlock on MI355X (gfx950).  Pipeline:
//   1. rmsnorm         : x f32 (8192x1024) -> xnorm bf16
//   2. weight packs    : W_in, W_dt, [W_B;W_C;pad] (128x2048), W_out -> bf16;
//                        A2 = -exp(A_log)*log2(e)
//   3. gemm256<2>      : xnorm @ W_in^T -> x_inner bf16 | silu(res) bf16
//   4. conv_silu       : depthwise causal K=4 + silu -> xconv bf16
//   5. gemm256<1>      : xconv @ W_dt^T -> dt f32 (softplus)
//   5b. gemm_bf16<3>   : xconv @ [WB;WC]^T -> bc f32 (skinny N=32)
//   6. scan            : chunked two-pass associative scan, channel-per-lane
//   7. gemm256<0>      : y @ W_out^T -> d_out f32
// R8: de-clobber the GEMM asm.  R7 arithmetic: ~4950 cyc/K-tile vs 310 MFMA
// + <=900 latency -> something drains every phase.  Theory: ":::memory"
// clobbers on waitcnt asm make SIInsertWaitcnts emit conservative
// vmcnt(0)/lgkmcnt(0) drains before each asm (outstanding LDS-DMA could
// alias) -> full prefetch-queue drain ~2x/tile, independent of depth.
// m201 template uses clobber-free waitcnt asm + sched_barrier(0) pins.
// Fix: clobber-free asm; SB0 after each lgkm0 (MFMA cluster stays below),
// SB0 before tile-end vmcnt (STGs can't sink past counted wait), SB0 after
// tile-end barrier (next-tile ds_reads can't hoist).  Schedule unchanged:
// BK=32, 4 LDS buffers, depth-3 prefetch, 2 phases x16 MFMA, vmcnt(8)/tile.
// ---------------------------------------------------------------------------

typedef __bf16 bf16;
typedef __attribute__((ext_vector_type(8))) __bf16 bf16x8;
typedef __attribute__((ext_vector_type(4))) float f32x4;

#define DIM   1024
#define STATE 16
#define INNER 2048
#define BATCH 4
#define SEQ   2048
#define ROWS  (BATCH * SEQ)      // 8192
#define N1    (2 * INNER)        // 4096 (GEMM1 N)
#define NBC   2176               // kept for workspace offsets
#define CHUNK 128                // scan chunk length
#define NC    (SEQ / CHUNK)      // 16 chunks per sequence
#define PF2   4                  // scan prefetch depth (rows)

// async global->LDS, 16 bytes per lane (lane-contiguous LDS dest)
#define GLOAD_LDS16(g, l)                                                  \
  __builtin_amdgcn_global_load_lds(                                        \
      (const __attribute__((address_space(1))) unsigned int*)(g),          \
      (__attribute__((address_space(3))) unsigned int*)(l), 16, 0, 0)

// ---------------------------------------------------------------------------
// 0. workspace-too-small diagnostic
// ---------------------------------------------------------------------------
__global__ void ws_report_kernel(float* out, float wssz, float need) {
  if (threadIdx.x == 0) { out[0] = wssz; out[1] = need; }
}

// ---------------------------------------------------------------------------
// 1. RMSNorm: one block per row (1024 floats), 256 threads x float4
// ---------------------------------------------------------------------------
__global__ __launch_bounds__(256) void rmsnorm_kernel(
    const float* __restrict__ x, const float* __restrict__ w,
    bf16* __restrict__ out) {
  const int row = blockIdx.x;
  const int t = threadIdx.x;
  const float4 v = ((const float4*)(x + (long)row * DIM))[t];
  float ss = v.x * v.x + v.y * v.y + v.z * v.z + v.w * v.w;
#pragma unroll
  for (int off = 32; off > 0; off >>= 1) ss += __shfl_xor(ss, off, 64);
  __shared__ float red[4];
  if ((t & 63) == 0) red[t >> 6] = ss;
  __syncthreads();
  const float tot = red[0] + red[1] + red[2] + red[3];
  const float scale = rsqrtf(tot * (1.0f / DIM) + 1e-6f);
  const float4 wv = ((const float4*)w)[t];
  bf16* o = out + (long)row * DIM + t * 4;
  o[0] = (bf16)(v.x * scale * wv.x);
  o[1] = (bf16)(v.y * scale * wv.y);
  o[2] = (bf16)(v.z * scale * wv.z);
  o[3] = (bf16)(v.w * scale * wv.w);
}

// ---------------------------------------------------------------------------
// 2. weight packs
// ---------------------------------------------------------------------------
__global__ __launch_bounds__(256) void cvt_bf16_kernel(
    const float* __restrict__ src, bf16* __restrict__ dst, int n) {
  const int i = blockIdx.x * 256 + threadIdx.x;
  if (i < n) dst[i] = (bf16)src[i];
}

// [WB;WC;zero-pad] -> 128 x 2048 bf16 (rows 0-15 B, 16-31 C, 32-127 zero)
__global__ __launch_bounds__(256) void build_wbc_kernel(
    const float* __restrict__ WB, const float* __restrict__ WC,
    bf16* __restrict__ dst) {
  const int i = blockIdx.x * 256 + threadIdx.x;  // < 128*2048
  const int r = i >> 11;
  const int k = i & (INNER - 1);
  float v = 0.0f;
  if (r < 16) v = WB[r * INNER + k];
  else if (r < 32) v = WC[(r - 16) * INNER + k];
  dst[i] = (bf16)v;
}

__global__ __launch_bounds__(256) void build_a2_kernel(
    const float* __restrict__ A_log, float* __restrict__ A2) {
  const int i = blockIdx.x * 256 + threadIdx.x;  // < INNER*STATE
  A2[i] = -__expf(A_log[i]) * 1.4426950408889634f;  // A * log2(e)
}

// ---------------------------------------------------------------------------
// 3/5/7. GEMM 256x256 deep-prefetch: C[M,N] = A[M,K] @ B[N,K]^T (bf16,f32acc)
// 512 threads = 8 waves (2M x 4N); per-wave 128x64 out (8x4 16x16 frags).
// BK=32, LDS 4 buffers x (A 16K | B 16K) = 128 KiB, prefetch 3 tiles deep.
// Per tile: ph1 {ds_read A-lo+B, STG_A x2, BAR, lgkm0+SB0, prio1 16MFMA
// prio0, BAR}; ph2 {ds_read A-hi, STG_B x2, BAR, lgkm0+SB0, prio1 16MFMA
// prio0, SB0, vmcnt(8), BAR, SB0}.  All waitcnt asm clobber-free (clobbers
// trigger compiler vmcnt(0) drains); ordering via sched_barrier(0) pins.
// Swizzle (64B rows): byte ^= ((row>>1)&3)<<4 on global source and ds_read
// (involution; LDS dest linear per global_load_lds rule).
// EPI 0: plain f32 -> Cf (stride 256*NX)
// EPI 1: softplus(acc + bias) -> Cf (stride 2048)
// EPI 2: col0<2048 -> bf16 -> Cb; else silu -> Cb2 (both stride 2048)
// ---------------------------------------------------------------------------
template <int EPI, int K, int NX>
__global__ __launch_bounds__(512, 2) void gemm256_kernel(
    const bf16* __restrict__ A, const bf16* __restrict__ B,
    float* __restrict__ Cf, bf16* __restrict__ Cb, bf16* __restrict__ Cb2,
    const float* __restrict__ bias) {
  __shared__ __align__(16) char lds[4][32768];  // [buf][A 16K | B 16K]
  const int tid = threadIdx.x;
  const int lane = tid & 63;
  const int wave = tid >> 6;
  const int wm = wave >> 2;  // 0..1: M half (128 rows)
  const int wn = wave & 3;   // 0..3: N quarter (64 cols)

  // XCD-band swizzle (grid % 8 == 0): contiguous row-tile band per XCD.
  const int per = gridDim.x >> 3;
  const int lin = (blockIdx.x & 7) * per + (blockIdx.x >> 3);
  const int row_t = lin / NX;
  const int col_t = lin - row_t * NX;
  const long row0 = (long)row_t * 256;
  const long col0 = (long)col_t * 256;

  // ---- staging: 512 threads x 16B = 8KB/round; 2 rounds per A (B) tile ----
  const int srow = tid >> 2;                   // 0..127
  const int scb = (tid & 3) * 16;              // 0,16,32,48 (linear LDS dest)
  const int ssw = scb ^ (((srow >> 1) & 3) << 4);  // inv-swizzled source col
  const char* gA = (const char*)A + (row0 + srow) * (long)(2 * K) + ssw;
  const char* gB = (const char*)B + (col0 + srow) * (long)(2 * K) + ssw;

#define STG_A(bb, r, tt)                                                      \
  GLOAD_LDS16(gA + (long)(r) * 128 * (2 * K) + (long)(tt) * 64,               \
              lds[bb] + (r) * 8192 + srow * 64 + scb)
#define STG_B(bb, r, tt)                                                      \
  GLOAD_LDS16(gB + (long)(r) * 128 * (2 * K) + (long)(tt) * 64,               \
              lds[bb] + 16384 + (r) * 8192 + srow * 64 + scb)

  // ---- fragment read addressing (swizzled) ----
  const int fm = lane & 15;
  const int fq = lane >> 4;
  const int ck = (fq * 16) ^ (((fm >> 1) & 3) << 4);
  const int aro = (wm * 128 + fm) * 64;  // byte row offset in A region
  const int bro = (wn * 64 + fm) * 64;   // byte row offset in B region

  f32x4 acc[8][4];
#pragma unroll
  for (int i = 0; i < 8; ++i)
#pragma unroll
    for (int n = 0; n < 4; ++n) acc[i][n] = (f32x4){0.f, 0.f, 0.f, 0.f};
  bf16x8 afr[4], bfr[4];

  const int NT = K / 32;
  // prologue: stage tiles 0,1,2 (12 loads)
#pragma unroll
  for (int t = 0; t < 3; ++t) {
    STG_A(t, 0, t); STG_A(t, 1, t);
    STG_B(t, 0, t); STG_B(t, 1, t);
  }
  __builtin_amdgcn_sched_barrier(0);
  asm volatile("s_waitcnt vmcnt(8)");  // tile 0 landed
  __builtin_amdgcn_s_barrier();
  __builtin_amdgcn_sched_barrier(0);

  for (int t = 0; t < NT; ++t) {
    const int c = t & 3;
    const int pb = (t + 3) & 3;
    const char* Ac = lds[c];
    const char* Bc = lds[c] + 16384;
    const bool pf = (t + 3) < NT;
    // ---- phase 1: A-low + B frags; stage next A; MFMA i0-3 ----
#pragma unroll
    for (int i = 0; i < 4; ++i)
      afr[i] = *(const bf16x8*)(Ac + aro + i * 1024 + ck);
#pragma unroll
    for (int n = 0; n < 4; ++n)
      bfr[n] = *(const bf16x8*)(Bc + bro + n * 1024 + ck);
    if (pf) { STG_A(pb, 0, t + 3); STG_A(pb, 1, t + 3); }
    __builtin_amdgcn_s_barrier();
    asm volatile("s_waitcnt lgkmcnt(0)");
    __builtin_amdgcn_sched_barrier(0);
    __builtin_amdgcn_s_setprio(1);
#pragma unroll
    for (int i = 0; i < 4; ++i)
#pragma unroll
      for (int n = 0; n < 4; ++n)
        acc[i][n] = __builtin_amdgcn_mfma_f32_16x16x32_bf16(
            afr[i], bfr[n], acc[i][n], 0, 0, 0);
    __builtin_amdgcn_s_setprio(0);
    __builtin_amdgcn_s_barrier();
    // ---- phase 2: A-high frags; stage next B; MFMA i4-7 ----
#pragma unroll
    for (int i = 0; i < 4; ++i)
      afr[i] = *(const bf16x8*)(Ac + aro + (i + 4) * 1024 + ck);
    if (pf) { STG_B(pb, 0, t + 3); STG_B(pb, 1, t + 3); }
    __builtin_amdgcn_s_barrier();
    asm volatile("s_waitcnt lgkmcnt(0)");
    __builtin_amdgcn_sched_barrier(0);
    __builtin_amdgcn_s_setprio(1);
#pragma unroll
    for (int i = 0; i < 4; ++i)
#pragma unroll
      for (int n = 0; n < 4; ++n)
        acc[4 + i][n] = __builtin_amdgcn_mfma_f32_16x16x32_bf16(
            afr[i], bfr[n], acc[4 + i][n], 0, 0, 0);
    __builtin_amdgcn_s_setprio(0);
    // tile-end counted wait: SB0 pins STGs above the wait; then barrier.
    __builtin_amdgcn_sched_barrier(0);
    if (t < NT - 3) {
      asm volatile("s_waitcnt vmcnt(8)");   // tile t+1 landed; 8 in flight
    } else if (t == NT - 3) {
      asm volatile("s_waitcnt vmcnt(4)");
    } else if (t == NT - 2) {
      asm volatile("s_waitcnt vmcnt(0)");
    }
    __builtin_amdgcn_s_barrier();
    __builtin_amdgcn_sched_barrier(0);  // next tile's ds_reads stay below
  }
#undef STG_A
#undef STG_B

  // epilogue: C/D layout col=lane&15, row=(lane>>4)*4+reg  [m89/m91]
  const int er = fq * 4;
  const long rbase = row0 + wm * 128;
  const long cbase = col0 + wn * 64;
  if (EPI == 0) {
    const long Nn = 256 * NX;
#pragma unroll
    for (int i = 0; i < 8; ++i)
#pragma unroll
      for (int n = 0; n < 4; ++n) {
        const long col = cbase + n * 16 + fm;
        const long rw = rbase + i * 16 + er;
#pragma unroll
        for (int r = 0; r < 4; ++r) Cf[(rw + r) * Nn + col] = acc[i][n][r];
      }
  } else if (EPI == 1) {
#pragma unroll
    for (int i = 0; i < 8; ++i)
#pragma unroll
      for (int n = 0; n < 4; ++n) {
        const long col = cbase + n * 16 + fm;
        const float bs = bias[col];
        const long rw = rbase + i * 16 + er;
#pragma unroll
        for (int r = 0; r < 4; ++r) {
          float z = acc[i][n][r] + bs;
          z = (z > 20.0f) ? z : log1pf(__expf(z));
          Cf[(rw + r) * 2048 + col] = z;
        }
      }
  } else {  // EPI == 2 (2048-boundary is tile-aligned -> block-uniform)
    if (col0 < 2048) {
#pragma unroll
      for (int i = 0; i < 8; ++i)
#pragma unroll
        for (int n = 0; n < 4; ++n) {
          const long col = cbase + n * 16 + fm;
          const long rw = rbase + i * 16 + er;
#pragma unroll
          for (int r = 0; r < 4; ++r)
            Cb[(rw + r) * 2048 + col] = (bf16)acc[i][n][r];
        }
    } else {
#pragma unroll
      for (int i = 0; i < 8; ++i)
#pragma unroll
        for (int n = 0; n < 4; ++n) {
          const long col = cbase + n * 16 + fm - 2048;
          const long rw = rbase + i * 16 + er;
#pragma unroll
          for (int r = 0; r < 4; ++r) {
            const float v = acc[i][n][r];
            const float s = v / (1.0f + __expf(-v));
            Cb2[(rw + r) * 2048 + col] = (bf16)s;
          }
        }
    }
  }
}

// ---------------------------------------------------------------------------
// 5b. skinny GEMM (m97 128x128 structure): bc = xc @ [WB;WC]^T.
// N=128 (rows 32..127 of B are zero-pad); EPI 3 writes col<32 -> Cf2
// (stride 32).  grid 64 blocks.
// ---------------------------------------------------------------------------
template <int EPI>
__global__ __launch_bounds__(256) void gemm_bf16_kernel(
    const bf16* __restrict__ A, const bf16* __restrict__ B,
    float* __restrict__ Cf2, int nx, int N, int K) {
  __shared__ __align__(16) bf16 As[128 * 32];
  __shared__ __align__(16) bf16 Bs[128 * 32];
  const int tid = threadIdx.x;
  const int lane = tid & 63;
  const int wave = tid >> 6;

  const int per = gridDim.x >> 3;
  const int lin = (blockIdx.x & 7) * per + (blockIdx.x >> 3);
  const int row_t = lin / nx;
  const int col_t = lin - row_t * nx;
  const long row0 = (long)row_t * 128;
  const long col0 = (long)col_t * 128;

  const int wr = (wave >> 1) * 64;
  const int wc = (wave & 1) * 64;

  f32x4 acc[4][4];
#pragma unroll
  for (int i = 0; i < 4; i++)
#pragma unroll
    for (int j = 0; j < 4; j++) acc[i][j] = (f32x4){0.f, 0.f, 0.f, 0.f};

  const int srow = tid >> 2;
  const int scol = (tid & 3) * 8;
  const bf16* gA0 = A + (row0 + srow) * (long)K + scol;
  const bf16* gA1 = A + (row0 + srow + 64) * (long)K + scol;
  const bf16* gB0 = B + (col0 + srow) * (long)K + scol;
  const bf16* gB1 = B + (col0 + srow + 64) * (long)K + scol;
  bf16* lA0 = As + wave * 512 + lane * 8;
  bf16* lA1 = As + 64 * 32 + wave * 512 + lane * 8;
  bf16* lB0 = Bs + wave * 512 + lane * 8;
  bf16* lB1 = Bs + 64 * 32 + wave * 512 + lane * 8;

  const int fm = lane & 15;
  const int fk = (lane >> 4) * 8;

  for (int k0 = 0; k0 < K; k0 += 32) {
    GLOAD_LDS16(gA0 + k0, lA0);
    GLOAD_LDS16(gA1 + k0, lA1);
    GLOAD_LDS16(gB0 + k0, lB0);
    GLOAD_LDS16(gB1 + k0, lB1);
    __syncthreads();
    bf16x8 af[4], bfv[4];
#pragma unroll
    for (int i = 0; i < 4; i++)
      af[i] = *(const bf16x8*)(As + (wr + i * 16 + fm) * 32 + fk);
#pragma unroll
    for (int j = 0; j < 4; j++)
      bfv[j] = *(const bf16x8*)(Bs + (wc + j * 16 + fm) * 32 + fk);
#pragma unroll
    for (int i = 0; i < 4; i++)
#pragma unroll
      for (int j = 0; j < 4; j++)
        acc[i][j] = __builtin_amdgcn_mfma_f32_16x16x32_bf16(
            af[i], bfv[j], acc[i][j], 0, 0, 0);
    __syncthreads();
  }

  const int er = (lane >> 4) * 4;
  const int ec = lane & 15;
#pragma unroll
  for (int i = 0; i < 4; i++) {
#pragma unroll
    for (int j = 0; j < 4; j++) {
      const long col = col0 + wc + j * 16 + ec;
      const long rw = row0 + wr + i * 16 + er;
#pragma unroll
      for (int r = 0; r < 4; r++) {
        const float v = acc[i][j][r];
        const long row = rw + r;
        if (EPI == 3) {
          if (col < 32) Cf2[row * 32 + col] = v;  // wc==0 && j<2 only
        }
      }
    }
  }
}

// ---------------------------------------------------------------------------
// 4. depthwise causal conv (K=4) + silu.  xin: ROWS x 2048 bf16
// ---------------------------------------------------------------------------
__global__ __launch_bounds__(256) void conv_silu_kernel(
    const bf16* __restrict__ xin, const float* __restrict__ conv_w,
    const float* __restrict__ conv_b, bf16* __restrict__ xc16) {
  const int c = blockIdx.x * 256 + threadIdx.x;  // channel 0..2047
  const int r = blockIdx.y;                      // global row 0..8191
  const int l = r & (SEQ - 1);                   // position within sequence
  const float4 w = *(const float4*)(conv_w + c * 4);
  float acc = conv_b[c];
#pragma unroll
  for (int j = 0; j < 4; j++) {
    const int lp = l - 3 + j;
    const float xv = (lp >= 0) ? (float)xin[(long)(r - 3 + j) * INNER + c] : 0.0f;
    acc += xv * ((const float*)&w)[j];
  }
  const float s = acc / (1.0f + __expf(-acc));  // silu
  xc16[(long)r * INNER + c] = (bf16)s;
}

// ---------------------------------------------------------------------------
// 6a. scan pass 1: per-chunk zero-init scan -> h_end0[16] + dt-sum.
// ---------------------------------------------------------------------------
__global__ __launch_bounds__(256) void scan_pass1_kernel(
    const float* __restrict__ dtm, const float* __restrict__ bc,
    const bf16* __restrict__ xc, const float* __restrict__ A2,
    float* __restrict__ hend, float* __restrict__ dtsum) {
  const int ch = blockIdx.x * 256 + threadIdx.x;
  const int c = blockIdx.y;
  const int b = blockIdx.z;
  const long row0 = (long)b * SEQ + (long)c * CHUNK;

  float a2[16];
#pragma unroll
  for (int q = 0; q < 4; q++) {
    const float4 t = ((const float4*)(A2 + (long)ch * 16))[q];
    a2[q * 4 + 0] = t.x; a2[q * 4 + 1] = t.y;
    a2[q * 4 + 2] = t.z; a2[q * 4 + 3] = t.w;
  }
  float h[16];
#pragma unroll
  for (int s = 0; s < 16; s++) h[s] = 0.0f;
  float dts = 0.0f;

  float dtq[PF2], xcq[PF2];
#pragma unroll
  for (int p = 0; p < PF2; p++) {
    const long r2 = row0 + p;
    dtq[p] = dtm[r2 * INNER + ch];
    xcq[p] = (float)xc[r2 * INNER + ch];
  }
  for (int l0 = 0; l0 <= CHUNK - 2 * PF2; l0 += PF2) {
#pragma unroll
    for (int p = 0; p < PF2; p++) {
      const float dt = dtq[p], xcv = xcq[p];
      const long rp = row0 + l0 + p + PF2;
      dtq[p] = dtm[rp * INNER + ch];
      xcq[p] = (float)xc[rp * INNER + ch];
      const long r = row0 + l0 + p;
      float Bv[16];  // wave-uniform -> scalar loads
#pragma unroll
      for (int k = 0; k < 16; k++) Bv[k] = bc[r * 32 + k];
      dts += dt;
      const float u = dt * xcv;
#pragma unroll
      for (int s = 0; s < 16; s++)
        h[s] = exp2f(a2[s] * dt) * h[s] + Bv[s] * u;
    }
  }
#pragma unroll
  for (int p = 0; p < PF2; p++) {
    const float dt = dtq[p], xcv = xcq[p];
    const long r = row0 + CHUNK - PF2 + p;
    float Bv[16];
#pragma unroll
    for (int k = 0; k < 16; k++) Bv[k] = bc[r * 32 + k];
    dts += dt;
    const float u = dt * xcv;
#pragma unroll
    for (int s = 0; s < 16; s++)
      h[s] = exp2f(a2[s] * dt) * h[s] + Bv[s] * u;
  }

  const long cb = (long)(b * NC + c);
#pragma unroll
  for (int s = 0; s < 16; s++) hend[(cb * 16 + s) * INNER + ch] = h[s];
  dtsum[cb * INNER + ch] = dts;
}

// ---------------------------------------------------------------------------
// 6b. combine: sequential over NC chunks; rewrites hend -> h_start in place.
// ---------------------------------------------------------------------------
__global__ __launch_bounds__(256) void scan_combine_kernel(
    float* __restrict__ hio, const float* __restrict__ dtsum,
    const float* __restrict__ A2) {
  const int idx = blockIdx.x * 256 + threadIdx.x;  // < BATCH*16*INNER
  const int ch = idx & (INNER - 1);
  const int s = (idx >> 11) & 15;
  const int b = idx >> 15;
  const float a2 = A2[(long)ch * 16 + s];
  float H = 0.0f;
  for (int c = 0; c < NC; c++) {
    const long cb = (long)(b * NC + c);
    const long o = (cb * 16 + s) * INNER + ch;
    const float he = hio[o];
    const float ds = dtsum[cb * INNER + ch];
    hio[o] = H;  // h_start for chunk c
    H = exp2f(a2 * ds) * H + he;
  }
}

// ---------------------------------------------------------------------------
// 6c. scan pass 3: re-scan chunk from true h_start; y = (C.h + D*xc)*silu(res)
// ---------------------------------------------------------------------------
__global__ __launch_bounds__(256) void scan_pass3_kernel(
    const float* __restrict__ dtm, const float* __restrict__ bc,
    const bf16* __restrict__ xc, const bf16* __restrict__ rs,
    const float* __restrict__ A2, const float* __restrict__ Dv,
    const float* __restrict__ hstart, bf16* __restrict__ y) {
  const int ch = blockIdx.x * 256 + threadIdx.x;
  const int c = blockIdx.y;
  const int b = blockIdx.z;
  const long row0 = (long)b * SEQ + (long)c * CHUNK;

  float a2[16];
#pragma unroll
  for (int q = 0; q < 4; q++) {
    const float4 t = ((const float4*)(A2 + (long)ch * 16))[q];
    a2[q * 4 + 0] = t.x; a2[q * 4 + 1] = t.y;
    a2[q * 4 + 2] = t.z; a2[q * 4 + 3] = t.w;
  }
  const float d = Dv[ch];
  const long cb = (long)(b * NC + c);
  float h[16];
#pragma unroll
  for (int s = 0; s < 16; s++) h[s] = hstart[(cb * 16 + s) * INNER + ch];

  float dtq[PF2], xcq[PF2], rsq[PF2];
#pragma unroll
  for (int p = 0; p < PF2; p++) {
    const long r2 = row0 + p;
    dtq[p] = dtm[r2 * INNER + ch];
    xcq[p] = (float)xc[r2 * INNER + ch];
    rsq[p] = (float)rs[r2 * INNER + ch];
  }
  for (int l0 = 0; l0 <= CHUNK - 2 * PF2; l0 += PF2) {
#pragma unroll
    for (int p = 0; p < PF2; p++) {
      const float dt = dtq[p], xcv = xcq[p], rsv = rsq[p];
      const long rp = row0 + l0 + p + PF2;
      dtq[p] = dtm[rp * INNER + ch];
      xcq[p] = (float)xc[rp * INNER + ch];
      rsq[p] = (float)rs[rp * INNER + ch];
      const long r = row0 + l0 + p;
      float Bv[16], Cv[16];  // wave-uniform -> scalar loads
#pragma unroll
      for (int k = 0; k < 16; k++) Bv[k] = bc[r * 32 + k];
#pragma unroll
      for (int k = 0; k < 16; k++) Cv[k] = bc[r * 32 + 16 + k];
      const float u = dt * xcv;
      float yv = d * xcv;
#pragma unroll
      for (int s = 0; s < 16; s++) {
        h[s] = exp2f(a2[s] * dt) * h[s] + Bv[s] * u;
        yv += h[s] * Cv[s];
      }
      y[r * INNER + ch] = (bf16)(yv * rsv);
    }
  }
#pragma unroll
  for (int p = 0; p < PF2; p++) {
    const float dt = dtq[p], xcv = xcq[p], rsv = rsq[p];
    const long r = row0 + CHUNK - PF2 + p;
    float Bv[16], Cv[16];
#pragma unroll
    for (int k = 0; k < 16; k++) Bv[k] = bc[r * 32 + k];
#pragma unroll
    for (int k = 0; k < 16; k++) Cv[k] = bc[r * 32 + 16 + k];
    const float u = dt * xcv;
    float yv = d * xcv;
#pragma unroll
    for (int s = 0; s < 16; s++) {
      h[s] = exp2f(a2[s] * dt) * h[s] + Bv[s] * u;
      yv += h[s] * Cv[s];
    }
    y[r * INNER + ch] = (bf16)(yv * rsv);
  }
}

// ---------------------------------------------------------------------------
// launch
// ---------------------------------------------------------------------------
extern "C" void kernel_launch(void* const* d_in, const int* in_sizes, int n_in,
                              void* d_out, int out_size, void* d_ws,
                              size_t ws_size, hipStream_t stream) {
  (void)in_sizes; (void)n_in; (void)out_size;
  const float* x      = (const float*)d_in[0];
  const float* w_norm = (const float*)d_in[1];
  const float* W_in   = (const float*)d_in[2];
  const float* conv_w = (const float*)d_in[3];
  const float* conv_b = (const float*)d_in[4];
  const float* W_dt   = (const float*)d_in[5];
  const float* b_dt   = (const float*)d_in[6];
  const float* W_B    = (const float*)d_in[7];
  const float* W_C    = (const float*)d_in[8];
  const float* A_log  = (const float*)d_in[9];
  const float* Dv     = (const float*)d_in[10];
  const float* W_out  = (const float*)d_in[11];
  float* out = (float*)d_out;

  // ---- workspace layout (lifetime-aliased, 173.625 MiB total) -------------
  const size_t MB = 1024ull * 1024ull;
  char* base = (char*)d_ws;
  bf16*  xnorm  = (bf16*)(base + 0);          // 16 MiB [rmsnorm -> gemm1]
  bf16*  win_b  = (bf16*)(base + 16 * MB);    //  8 MiB [pack -> gemm1]
  bf16*  xin_b  = (bf16*)(base + 24 * MB);    // 32 MiB [gemm1 -> conv]
  float* dtm    = (float*)(base + 0);         // 64 MiB [gemm2 -> scan] ALIAS
  float* bcm    = (float*)(base + 64 * MB);   //  1 MiB [bc-gemm -> scan]
  bf16*  res_b  = (bf16*)(base + 65 * MB);    // 32 MiB [gemm1 -> scan]
  bf16*  xc_b   = (bf16*)(base + 97 * MB);    // 32 MiB [conv -> gemm2, scan]
  bf16*  wdt_b  = (bf16*)(base + 129 * MB);   //  8 MiB [pack -> gemm2]
  bf16*  wbc_b  = (bf16*)(base + 137 * MB);   // 0.5 MiB [pack -> bc-gemm]
  // chunk state aliases wdt_b/wbc_b (dead after gemm2/bc):
  float* hend   = (float*)(base + 129 * MB);                 // 8 MiB
  float* dtsum  = (float*)(base + 137 * MB);                 // 0.5 MiB
  char*  p2     = base + 129 * MB + (size_t)NBC * INNER * 2; // = 137.5 MiB
  bf16*  wout_b = (bf16*)p2;                  //  4 MiB [pack -> gemm3]
  float* A2     = (float*)(p2 + (size_t)DIM * INNER * 2);  // 128 KiB
  bf16*  yb     = (bf16*)(p2 + (size_t)DIM * INNER * 2 +
                          (size_t)INNER * STATE * 4);      // 32 MiB [scan->g3]
  const size_t NEEDED = (size_t)((char*)yb - base) + (size_t)ROWS * INNER * 2;

  if (ws_size < NEEDED) {  // diagnostic: fail with absmax == ws_size
    ws_report_kernel<<<1, 64, 0, stream>>>(out, (float)ws_size, (float)NEEDED);
    return;
  }

  // 1. rmsnorm -> xnorm bf16
  rmsnorm_kernel<<<ROWS, 256, 0, stream>>>(x, w_norm, xnorm);

  // 2. weight packs
  cvt_bf16_kernel<<<(N1 * DIM) / 256, 256, 0, stream>>>(W_in, win_b, N1 * DIM);
  cvt_bf16_kernel<<<(INNER * INNER) / 256, 256, 0, stream>>>(W_dt, wdt_b,
                                                             INNER * INNER);
  build_wbc_kernel<<<(128 * INNER) / 256, 256, 0, stream>>>(W_B, W_C, wbc_b);
  cvt_bf16_kernel<<<(DIM * INNER) / 256, 256, 0, stream>>>(W_out, wout_b,
                                                           DIM * INNER);
  build_a2_kernel<<<(INNER * STATE) / 256, 256, 0, stream>>>(A_log, A2);

  // 3. GEMM1: xnorm(8192x1024) @ W_in^T(4096x1024) -> xin_b | silu->res_b
  //    grid 32x16=512 (2 clean generations)
  gemm256_kernel<2, 1024, 16><<<512, 512, 0, stream>>>(
      xnorm, win_b, nullptr, xin_b, res_b, nullptr);

  // 4. conv + silu -> xc_b
  conv_silu_kernel<<<dim3(INNER / 256, ROWS), 256, 0, stream>>>(
      xin_b, conv_w, conv_b, xc_b);

  // 5. GEMM2: xc_b(8192x2048) @ W_dt^T(2048x2048) -> dtm (softplus)
  //    grid 32x8=256 (1 clean generation)
  gemm256_kernel<1, 2048, 8><<<256, 512, 0, stream>>>(
      xc_b, wdt_b, dtm, nullptr, nullptr, b_dt);

  // 5b. bc = xc_b @ [WB;WC]^T -> bcm (8192x32), skinny N=128-pad GEMM
  gemm_bf16_kernel<3><<<64, 256, 0, stream>>>(xc_b, wbc_b, bcm, 1, 128, INNER);

  // 6. chunked scan: pass1 -> combine -> pass3
  scan_pass1_kernel<<<dim3(INNER / 256, NC, BATCH), 256, 0, stream>>>(
      dtm, bcm, xc_b, A2, hend, dtsum);
  scan_combine_kernel<<<(BATCH * 16 * INNER) / 256, 256, 0, stream>>>(
      hend, dtsum, A2);
  scan_pass3_kernel<<<dim3(INNER / 256, NC, BATCH), 256, 0, stream>>>(
      dtm, bcm, xc_b, res_b, A2, Dv, hend, yb);

  // 7. GEMM3: yb(8192x2048) @ W_out^T(1024x2048) -> out f32, grid 32x4=128
  gemm256_kernel<0, 2048, 4><<<128, 512, 0, stream>>>(
      yb, wout_b, out, nullptr, nullptr, nullptr);
}

// Round 5
// 647.482 us; speedup vs baseline: 1.0341x; 1.0341x over previous
//
#include <hip/hip_runtime.h>

// ---------------------------------------------------------------------------
// MambaBlock on MI355X (gfx950).  Pipeline:
//   1. rmsnorm         : x f32 (8192x1024) -> xnorm bf16
//   2. weight packs    : W_in, W_dt, [W_B;W_C;pad] (128x2048), W_out -> bf16;
//                        A2 = -exp(A_log)*log2(e)
//   3. gemm256<2>      : xnorm @ W_in^T -> x_inner bf16 | silu(res) bf16
//   4. conv_silu       : depthwise causal K=4 + silu -> xconv bf16
//   5. gemm256<1>      : xconv @ W_dt^T -> dt f32 (softplus)
//   5b. gemm_bf16<3>   : xconv @ [WB;WC]^T -> bc f32 (skinny N=32)
//   6. scan            : chunked two-pass associative scan, channel-per-lane
//   7. gemm256<0>      : y @ W_out^T -> d_out f32
// R10: un-lockstep the K-loop.  Correct MFMA cost (m06: 2075 TF 16x16 =>
// ~19.4 cyc/MFMA/SIMD) gives a 1240-cyc/K-tile MFMA floor for the 256^2
// tile; measured 4300 cyc/tile @ MfmaUtil 22% = floor/0.29.  With 128 KiB
// LDS -> 1 block/CU, the 6-barrier/tile phase lockstep serializes
// {reads}->{MFMA} with no inter-block overlap: ~reads 375 + MFMA 1240 +
// 6 barrier spreads ~= measured.  Fix: ONE barrier per tile; issue all 12
// ds_reads + 4 STGs up front; NO manual lgkmcnt (compiler inserts precise
// counted lgkmcnt from register deps - m97-verified behavior); counted
// vmcnt(8) depth-3 prefetch kept.  SB0 only before vmcnt (STG sinking below
// would void the count - correctness) and after the barrier (no cross-tile
// hoist).  Buffer index compile-time via 4x manual unroll (NT % 4 == 0).
// Bank-conflict=0 in R7/R8 was a GOOD sign: swizzle is at the b128 minimum
// (8 lanes/16B slot), reads were real ds_read_b128 all along.
// ---------------------------------------------------------------------------

typedef __bf16 bf16;
typedef __attribute__((ext_vector_type(8))) __bf16 bf16x8;
typedef __attribute__((ext_vector_type(4))) float f32x4;

#define DIM   1024
#define STATE 16
#define INNER 2048
#define BATCH 4
#define SEQ   2048
#define ROWS  (BATCH * SEQ)      // 8192
#define N1    (2 * INNER)        // 4096 (GEMM1 N)
#define NBC   2176               // kept for workspace offsets
#define CHUNK 128                // scan chunk length
#define NC    (SEQ / CHUNK)      // 16 chunks per sequence
#define PF2   4                  // scan prefetch depth (rows)

// async global->LDS, 16 bytes per lane (lane-contiguous LDS dest)
#define GLOAD_LDS16(g, l)                                                  \
  __builtin_amdgcn_global_load_lds(                                        \
      (const __attribute__((address_space(1))) unsigned int*)(g),          \
      (__attribute__((address_space(3))) unsigned int*)(l), 16, 0, 0)

// ---------------------------------------------------------------------------
// 0. workspace-too-small diagnostic
// ---------------------------------------------------------------------------
__global__ void ws_report_kernel(float* out, float wssz, float need) {
  if (threadIdx.x == 0) { out[0] = wssz; out[1] = need; }
}

// ---------------------------------------------------------------------------
// 1. RMSNorm: one block per row (1024 floats), 256 threads x float4
// ---------------------------------------------------------------------------
__global__ __launch_bounds__(256) void rmsnorm_kernel(
    const float* __restrict__ x, const float* __restrict__ w,
    bf16* __restrict__ out) {
  const int row = blockIdx.x;
  const int t = threadIdx.x;
  const float4 v = ((const float4*)(x + (long)row * DIM))[t];
  float ss = v.x * v.x + v.y * v.y + v.z * v.z + v.w * v.w;
#pragma unroll
  for (int off = 32; off > 0; off >>= 1) ss += __shfl_xor(ss, off, 64);
  __shared__ float red[4];
  if ((t & 63) == 0) red[t >> 6] = ss;
  __syncthreads();
  const float tot = red[0] + red[1] + red[2] + red[3];
  const float scale = rsqrtf(tot * (1.0f / DIM) + 1e-6f);
  const float4 wv = ((const float4*)w)[t];
  bf16* o = out + (long)row * DIM + t * 4;
  o[0] = (bf16)(v.x * scale * wv.x);
  o[1] = (bf16)(v.y * scale * wv.y);
  o[2] = (bf16)(v.z * scale * wv.z);
  o[3] = (bf16)(v.w * scale * wv.w);
}

// ---------------------------------------------------------------------------
// 2. weight packs
// ---------------------------------------------------------------------------
__global__ __launch_bounds__(256) void cvt_bf16_kernel(
    const float* __restrict__ src, bf16* __restrict__ dst, int n) {
  const int i = blockIdx.x * 256 + threadIdx.x;
  if (i < n) dst[i] = (bf16)src[i];
}

// [WB;WC;zero-pad] -> 128 x 2048 bf16 (rows 0-15 B, 16-31 C, 32-127 zero)
__global__ __launch_bounds__(256) void build_wbc_kernel(
    const float* __restrict__ WB, const float* __restrict__ WC,
    bf16* __restrict__ dst) {
  const int i = blockIdx.x * 256 + threadIdx.x;  // < 128*2048
  const int r = i >> 11;
  const int k = i & (INNER - 1);
  float v = 0.0f;
  if (r < 16) v = WB[r * INNER + k];
  else if (r < 32) v = WC[(r - 16) * INNER + k];
  dst[i] = (bf16)v;
}

__global__ __launch_bounds__(256) void build_a2_kernel(
    const float* __restrict__ A_log, float* __restrict__ A2) {
  const int i = blockIdx.x * 256 + threadIdx.x;  // < INNER*STATE
  A2[i] = -__expf(A_log[i]) * 1.4426950408889634f;  // A * log2(e)
}

// ---------------------------------------------------------------------------
// 3/5/7. GEMM 256x256: C[M,N] = A[M,K] @ B[N,K]^T (bf16, f32 acc)
// 512 threads = 8 waves (2M x 4N); per-wave 128x64 out (8x4 16x16 frags).
// BK=32, LDS 4 buffers x (A 16K | B 16K) = 128 KiB, prefetch 3 tiles deep.
// Per K-tile (ONE barrier): issue 12 ds_reads + 4 STG(t+3); setprio(1);
// 32 MFMA (compiler inserts precise counted lgkmcnt from reg deps);
// setprio(0); SB0; vmcnt(8); s_barrier; SB0.  vmcnt(8) = own-wave loads for
// tile t+1 landed; barrier publishes all waves' contributions.
// Swizzle (64B rows): byte ^= ((row>>1)&3)<<4 on global source and ds_read
// (involution; LDS dest linear) -> exactly 8 lanes/16B slot (b128 minimum).
// EPI 0: plain f32 -> Cf (stride 256*NX)
// EPI 1: softplus(acc + bias) -> Cf (stride 2048)
// EPI 2: col0<2048 -> bf16 -> Cb; else silu -> Cb2 (both stride 2048)
// ---------------------------------------------------------------------------
template <int EPI, int K, int NX>
__global__ __launch_bounds__(512, 2) void gemm256_kernel(
    const bf16* __restrict__ A, const bf16* __restrict__ B,
    float* __restrict__ Cf, bf16* __restrict__ Cb, bf16* __restrict__ Cb2,
    const float* __restrict__ bias) {
  __shared__ __align__(16) char lds[4][32768];  // [buf][A 16K | B 16K]
  const int tid = threadIdx.x;
  const int lane = tid & 63;
  const int wave = tid >> 6;
  const int wm = wave >> 2;  // 0..1: M half (128 rows)
  const int wn = wave & 3;   // 0..3: N quarter (64 cols)

  // XCD-band swizzle (grid % 8 == 0): contiguous row-tile band per XCD.
  const int per = gridDim.x >> 3;
  const int lin = (blockIdx.x & 7) * per + (blockIdx.x >> 3);
  const int row_t = lin / NX;
  const int col_t = lin - row_t * NX;
  const long row0 = (long)row_t * 256;
  const long col0 = (long)col_t * 256;

  // ---- staging: 512 threads x 16B = 8KB/round; 2 rounds per A (B) tile ----
  const int srow = tid >> 2;                   // 0..127
  const int scb = (tid & 3) * 16;              // 0,16,32,48 (linear LDS dest)
  const int ssw = scb ^ (((srow >> 1) & 3) << 4);  // inv-swizzled source col
  const char* gA = (const char*)A + (row0 + srow) * (long)(2 * K) + ssw;
  const char* gB = (const char*)B + (col0 + srow) * (long)(2 * K) + ssw;

#define STG_A(bb, r, tt)                                                      \
  GLOAD_LDS16(gA + (long)(r) * 128 * (2 * K) + (long)(tt) * 64,               \
              lds[bb] + (r) * 8192 + srow * 64 + scb)
#define STG_B(bb, r, tt)                                                      \
  GLOAD_LDS16(gB + (long)(r) * 128 * (2 * K) + (long)(tt) * 64,               \
              lds[bb] + 16384 + (r) * 8192 + srow * 64 + scb)

  // ---- fragment read addressing (swizzled) ----
  const int fm = lane & 15;
  const int fq = lane >> 4;
  const int ck = (fq * 16) ^ (((fm >> 1) & 3) << 4);
  const int aro = (wm * 128 + fm) * 64;  // byte row offset in A region
  const int bro = (wn * 64 + fm) * 64;   // byte row offset in B region

  f32x4 acc[8][4];
#pragma unroll
  for (int i = 0; i < 8; ++i)
#pragma unroll
    for (int n = 0; n < 4; ++n) acc[i][n] = (f32x4){0.f, 0.f, 0.f, 0.f};

  const int NT = K / 32;  // multiple of 4 for all instantiations
  // prologue: stage tiles 0,1,2 (12 loads)
#pragma unroll
  for (int t0 = 0; t0 < 3; ++t0) {
    STG_A(t0, 0, t0); STG_A(t0, 1, t0);
    STG_B(t0, 0, t0); STG_B(t0, 1, t0);
  }
  __builtin_amdgcn_sched_barrier(0);
  asm volatile("s_waitcnt vmcnt(8)");  // tile 0 landed (own wave)
  __builtin_amdgcn_s_barrier();
  __builtin_amdgcn_sched_barrier(0);

  // One K-tile.  CI is a literal constant -> lds[CI] is a constant GEP
  // (guaranteed addrspace(3) inference; R5-proven access pattern).
#define TILE_STEP(CI)                                                         \
  {                                                                           \
    const bool pf = (t + 3) < NT;                                             \
    bf16x8 al[4], bh[4], ah[4];                                               \
    _Pragma("unroll") for (int i = 0; i < 4; ++i)                             \
        al[i] = *(const bf16x8*)(lds[CI] + aro + i * 1024 + ck);              \
    _Pragma("unroll") for (int n = 0; n < 4; ++n)                             \
        bh[n] = *(const bf16x8*)(lds[CI] + 16384 + bro + n * 1024 + ck);      \
    _Pragma("unroll") for (int i = 0; i < 4; ++i)                             \
        ah[i] = *(const bf16x8*)(lds[CI] + aro + (i + 4) * 1024 + ck);        \
    if (pf) {                                                                 \
      STG_A((CI + 3) & 3, 0, t + 3); STG_A((CI + 3) & 3, 1, t + 3);           \
      STG_B((CI + 3) & 3, 0, t + 3); STG_B((CI + 3) & 3, 1, t + 3);           \
    }                                                                         \
    __builtin_amdgcn_s_setprio(1);                                            \
    _Pragma("unroll") for (int i = 0; i < 4; ++i)                             \
    _Pragma("unroll") for (int n = 0; n < 4; ++n)                             \
        acc[i][n] = __builtin_amdgcn_mfma_f32_16x16x32_bf16(                  \
            al[i], bh[n], acc[i][n], 0, 0, 0);                                \
    _Pragma("unroll") for (int i = 0; i < 4; ++i)                             \
    _Pragma("unroll") for (int n = 0; n < 4; ++n)                             \
        acc[4 + i][n] = __builtin_amdgcn_mfma_f32_16x16x32_bf16(              \
            ah[i], bh[n], acc[4 + i][n], 0, 0, 0);                            \
    __builtin_amdgcn_s_setprio(0);                                            \
    __builtin_amdgcn_sched_barrier(0); /* STGs may NOT sink below vmcnt */    \
    if (t < NT - 3) {                                                         \
      asm volatile("s_waitcnt vmcnt(8)");                                     \
    } else if (t == NT - 3) {                                                 \
      asm volatile("s_waitcnt vmcnt(4)");                                     \
    } else if (t == NT - 2) {                                                 \
      asm volatile("s_waitcnt vmcnt(0)");                                     \
    }                                                                         \
    __builtin_amdgcn_s_barrier();                                             \
    __builtin_amdgcn_sched_barrier(0); /* no cross-tile hoist */              \
    ++t;                                                                      \
  }

  {
    int t = 0;
    for (int tb = 0; tb < NT / 4; ++tb) {
      TILE_STEP(0)
      TILE_STEP(1)
      TILE_STEP(2)
      TILE_STEP(3)
    }
  }
#undef TILE_STEP
#undef STG_A
#undef STG_B

  // epilogue: C/D layout col=lane&15, row=(lane>>4)*4+reg  [m89/m91]
  const int er = fq * 4;
  const long rbase = row0 + wm * 128;
  const long cbase = col0 + wn * 64;
  if (EPI == 0) {
    const long Nn = 256 * NX;
#pragma unroll
    for (int i = 0; i < 8; ++i)
#pragma unroll
      for (int n = 0; n < 4; ++n) {
        const long col = cbase + n * 16 + fm;
        const long rw = rbase + i * 16 + er;
#pragma unroll
        for (int r = 0; r < 4; ++r) Cf[(rw + r) * Nn + col] = acc[i][n][r];
      }
  } else if (EPI == 1) {
#pragma unroll
    for (int i = 0; i < 8; ++i)
#pragma unroll
      for (int n = 0; n < 4; ++n) {
        const long col = cbase + n * 16 + fm;
        const float bs = bias[col];
        const long rw = rbase + i * 16 + er;
#pragma unroll
        for (int r = 0; r < 4; ++r) {
          float z = acc[i][n][r] + bs;
          z = (z > 20.0f) ? z : log1pf(__expf(z));
          Cf[(rw + r) * 2048 + col] = z;
        }
      }
  } else {  // EPI == 2 (2048-boundary is tile-aligned -> block-uniform)
    if (col0 < 2048) {
#pragma unroll
      for (int i = 0; i < 8; ++i)
#pragma unroll
        for (int n = 0; n < 4; ++n) {
          const long col = cbase + n * 16 + fm;
          const long rw = rbase + i * 16 + er;
#pragma unroll
          for (int r = 0; r < 4; ++r)
            Cb[(rw + r) * 2048 + col] = (bf16)acc[i][n][r];
        }
    } else {
#pragma unroll
      for (int i = 0; i < 8; ++i)
#pragma unroll
        for (int n = 0; n < 4; ++n) {
          const long col = cbase + n * 16 + fm - 2048;
          const long rw = rbase + i * 16 + er;
#pragma unroll
          for (int r = 0; r < 4; ++r) {
            const float v = acc[i][n][r];
            const float s = v / (1.0f + __expf(-v));
            Cb2[(rw + r) * 2048 + col] = (bf16)s;
          }
        }
    }
  }
}

// ---------------------------------------------------------------------------
// 5b. skinny GEMM (m97 128x128 structure): bc = xc @ [WB;WC]^T.
// N=128 (rows 32..127 of B are zero-pad); EPI 3 writes col<32 -> Cf2
// (stride 32).  grid 64 blocks.
// ---------------------------------------------------------------------------
template <int EPI>
__global__ __launch_bounds__(256) void gemm_bf16_kernel(
    const bf16* __restrict__ A, const bf16* __restrict__ B,
    float* __restrict__ Cf2, int nx, int N, int K) {
  __shared__ __align__(16) bf16 As[128 * 32];
  __shared__ __align__(16) bf16 Bs[128 * 32];
  const int tid = threadIdx.x;
  const int lane = tid & 63;
  const int wave = tid >> 6;

  const int per = gridDim.x >> 3;
  const int lin = (blockIdx.x & 7) * per + (blockIdx.x >> 3);
  const int row_t = lin / nx;
  const int col_t = lin - row_t * nx;
  const long row0 = (long)row_t * 128;
  const long col0 = (long)col_t * 128;

  const int wr = (wave >> 1) * 64;
  const int wc = (wave & 1) * 64;

  f32x4 acc[4][4];
#pragma unroll
  for (int i = 0; i < 4; i++)
#pragma unroll
    for (int j = 0; j < 4; j++) acc[i][j] = (f32x4){0.f, 0.f, 0.f, 0.f};

  const int srow = tid >> 2;
  const int scol = (tid & 3) * 8;
  const bf16* gA0 = A + (row0 + srow) * (long)K + scol;
  const bf16* gA1 = A + (row0 + srow + 64) * (long)K + scol;
  const bf16* gB0 = B + (col0 + srow) * (long)K + scol;
  const bf16* gB1 = B + (col0 + srow + 64) * (long)K + scol;
  bf16* lA0 = As + wave * 512 + lane * 8;
  bf16* lA1 = As + 64 * 32 + wave * 512 + lane * 8;
  bf16* lB0 = Bs + wave * 512 + lane * 8;
  bf16* lB1 = Bs + 64 * 32 + wave * 512 + lane * 8;

  const int fm = lane & 15;
  const int fk = (lane >> 4) * 8;

  for (int k0 = 0; k0 < K; k0 += 32) {
    GLOAD_LDS16(gA0 + k0, lA0);
    GLOAD_LDS16(gA1 + k0, lA1);
    GLOAD_LDS16(gB0 + k0, lB0);
    GLOAD_LDS16(gB1 + k0, lB1);
    __syncthreads();
    bf16x8 af[4], bfv[4];
#pragma unroll
    for (int i = 0; i < 4; i++)
      af[i] = *(const bf16x8*)(As + (wr + i * 16 + fm) * 32 + fk);
#pragma unroll
    for (int j = 0; j < 4; j++)
      bfv[j] = *(const bf16x8*)(Bs + (wc + j * 16 + fm) * 32 + fk);
#pragma unroll
    for (int i = 0; i < 4; i++)
#pragma unroll
      for (int j = 0; j < 4; j++)
        acc[i][j] = __builtin_amdgcn_mfma_f32_16x16x32_bf16(
            af[i], bfv[j], acc[i][j], 0, 0, 0);
    __syncthreads();
  }

  const int er = (lane >> 4) * 4;
  const int ec = lane & 15;
#pragma unroll
  for (int i = 0; i < 4; i++) {
#pragma unroll
    for (int j = 0; j < 4; j++) {
      const long col = col0 + wc + j * 16 + ec;
      const long rw = row0 + wr + i * 16 + er;
#pragma unroll
      for (int r = 0; r < 4; r++) {
        const float v = acc[i][j][r];
        const long row = rw + r;
        if (EPI == 3) {
          if (col < 32) Cf2[row * 32 + col] = v;  // wc==0 && j<2 only
        }
      }
    }
  }
}

// ---------------------------------------------------------------------------
// 4. depthwise causal conv (K=4) + silu.  xin: ROWS x 2048 bf16
// ---------------------------------------------------------------------------
__global__ __launch_bounds__(256) void conv_silu_kernel(
    const bf16* __restrict__ xin, const float* __restrict__ conv_w,
    const float* __restrict__ conv_b, bf16* __restrict__ xc16) {
  const int c = blockIdx.x * 256 + threadIdx.x;  // channel 0..2047
  const int r = blockIdx.y;                      // global row 0..8191
  const int l = r & (SEQ - 1);                   // position within sequence
  const float4 w = *(const float4*)(conv_w + c * 4);
  float acc = conv_b[c];
#pragma unroll
  for (int j = 0; j < 4; j++) {
    const int lp = l - 3 + j;
    const float xv = (lp >= 0) ? (float)xin[(long)(r - 3 + j) * INNER + c] : 0.0f;
    acc += xv * ((const float*)&w)[j];
  }
  const float s = acc / (1.0f + __expf(-acc));  // silu
  xc16[(long)r * INNER + c] = (bf16)s;
}

// ---------------------------------------------------------------------------
// 6a. scan pass 1: per-chunk zero-init scan -> h_end0[16] + dt-sum.
// ---------------------------------------------------------------------------
__global__ __launch_bounds__(256) void scan_pass1_kernel(
    const float* __restrict__ dtm, const float* __restrict__ bc,
    const bf16* __restrict__ xc, const float* __restrict__ A2,
    float* __restrict__ hend, float* __restrict__ dtsum) {
  const int ch = blockIdx.x * 256 + threadIdx.x;
  const int c = blockIdx.y;
  const int b = blockIdx.z;
  const long row0 = (long)b * SEQ + (long)c * CHUNK;

  float a2[16];
#pragma unroll
  for (int q = 0; q < 4; q++) {
    const float4 t = ((const float4*)(A2 + (long)ch * 16))[q];
    a2[q * 4 + 0] = t.x; a2[q * 4 + 1] = t.y;
    a2[q * 4 + 2] = t.z; a2[q * 4 + 3] = t.w;
  }
  float h[16];
#pragma unroll
  for (int s = 0; s < 16; s++) h[s] = 0.0f;
  float dts = 0.0f;

  float dtq[PF2], xcq[PF2];
#pragma unroll
  for (int p = 0; p < PF2; p++) {
    const long r2 = row0 + p;
    dtq[p] = dtm[r2 * INNER + ch];
    xcq[p] = (float)xc[r2 * INNER + ch];
  }
  for (int l0 = 0; l0 <= CHUNK - 2 * PF2; l0 += PF2) {
#pragma unroll
    for (int p = 0; p < PF2; p++) {
      const float dt = dtq[p], xcv = xcq[p];
      const long rp = row0 + l0 + p + PF2;
      dtq[p] = dtm[rp * INNER + ch];
      xcq[p] = (float)xc[rp * INNER + ch];
      const long r = row0 + l0 + p;
      float Bv[16];  // wave-uniform -> scalar loads
#pragma unroll
      for (int k = 0; k < 16; k++) Bv[k] = bc[r * 32 + k];
      dts += dt;
      const float u = dt * xcv;
#pragma unroll
      for (int s = 0; s < 16; s++)
        h[s] = exp2f(a2[s] * dt) * h[s] + Bv[s] * u;
    }
  }
#pragma unroll
  for (int p = 0; p < PF2; p++) {
    const float dt = dtq[p], xcv = xcq[p];
    const long r = row0 + CHUNK - PF2 + p;
    float Bv[16];
#pragma unroll
    for (int k = 0; k < 16; k++) Bv[k] = bc[r * 32 + k];
    dts += dt;
    const float u = dt * xcv;
#pragma unroll
    for (int s = 0; s < 16; s++)
      h[s] = exp2f(a2[s] * dt) * h[s] + Bv[s] * u;
  }

  const long cb = (long)(b * NC + c);
#pragma unroll
  for (int s = 0; s < 16; s++) hend[(cb * 16 + s) * INNER + ch] = h[s];
  dtsum[cb * INNER + ch] = dts;
}

// ---------------------------------------------------------------------------
// 6b. combine: sequential over NC chunks; rewrites hend -> h_start in place.
// ---------------------------------------------------------------------------
__global__ __launch_bounds__(256) void scan_combine_kernel(
    float* __restrict__ hio, const float* __restrict__ dtsum,
    const float* __restrict__ A2) {
  const int idx = blockIdx.x * 256 + threadIdx.x;  // < BATCH*16*INNER
  const int ch = idx & (INNER - 1);
  const int s = (idx >> 11) & 15;
  const int b = idx >> 15;
  const float a2 = A2[(long)ch * 16 + s];
  float H = 0.0f;
  for (int c = 0; c < NC; c++) {
    const long cb = (long)(b * NC + c);
    const long o = (cb * 16 + s) * INNER + ch;
    const float he = hio[o];
    const float ds = dtsum[cb * INNER + ch];
    hio[o] = H;  // h_start for chunk c
    H = exp2f(a2 * ds) * H + he;
  }
}

// ---------------------------------------------------------------------------
// 6c. scan pass 3: re-scan chunk from true h_start; y = (C.h + D*xc)*silu(res)
// ---------------------------------------------------------------------------
__global__ __launch_bounds__(256) void scan_pass3_kernel(
    const float* __restrict__ dtm, const float* __restrict__ bc,
    const bf16* __restrict__ xc, const bf16* __restrict__ rs,
    const float* __restrict__ A2, const float* __restrict__ Dv,
    const float* __restrict__ hstart, bf16* __restrict__ y) {
  const int ch = blockIdx.x * 256 + threadIdx.x;
  const int c = blockIdx.y;
  const int b = blockIdx.z;
  const long row0 = (long)b * SEQ + (long)c * CHUNK;

  float a2[16];
#pragma unroll
  for (int q = 0; q < 4; q++) {
    const float4 t = ((const float4*)(A2 + (long)ch * 16))[q];
    a2[q * 4 + 0] = t.x; a2[q * 4 + 1] = t.y;
    a2[q * 4 + 2] = t.z; a2[q * 4 + 3] = t.w;
  }
  const float d = Dv[ch];
  const long cb = (long)(b * NC + c);
  float h[16];
#pragma unroll
  for (int s = 0; s < 16; s++) h[s] = hstart[(cb * 16 + s) * INNER + ch];

  float dtq[PF2], xcq[PF2], rsq[PF2];
#pragma unroll
  for (int p = 0; p < PF2; p++) {
    const long r2 = row0 + p;
    dtq[p] = dtm[r2 * INNER + ch];
    xcq[p] = (float)xc[r2 * INNER + ch];
    rsq[p] = (float)rs[r2 * INNER + ch];
  }
  for (int l0 = 0; l0 <= CHUNK - 2 * PF2; l0 += PF2) {
#pragma unroll
    for (int p = 0; p < PF2; p++) {
      const float dt = dtq[p], xcv = xcq[p], rsv = rsq[p];
      const long rp = row0 + l0 + p + PF2;
      dtq[p] = dtm[rp * INNER + ch];
      xcq[p] = (float)xc[rp * INNER + ch];
      rsq[p] = (float)rs[rp * INNER + ch];
      const long r = row0 + l0 + p;
      float Bv[16], Cv[16];  // wave-uniform -> scalar loads
#pragma unroll
      for (int k = 0; k < 16; k++) Bv[k] = bc[r * 32 + k];
#pragma unroll
      for (int k = 0; k < 16; k++) Cv[k] = bc[r * 32 + 16 + k];
      const float u = dt * xcv;
      float yv = d * xcv;
#pragma unroll
      for (int s = 0; s < 16; s++) {
        h[s] = exp2f(a2[s] * dt) * h[s] + Bv[s] * u;
        yv += h[s] * Cv[s];
      }
      y[r * INNER + ch] = (bf16)(yv * rsv);
    }
  }
#pragma unroll
  for (int p = 0; p < PF2; p++) {
    const float dt = dtq[p], xcv = xcq[p], rsv = rsq[p];
    const long r = row0 + CHUNK - PF2 + p;
    float Bv[16], Cv[16];
#pragma unroll
    for (int k = 0; k < 16; k++) Bv[k] = bc[r * 32 + k];
#pragma unroll
    for (int k = 0; k < 16; k++) Cv[k] = bc[r * 32 + 16 + k];
    const float u = dt * xcv;
    float yv = d * xcv;
#pragma unroll
    for (int s = 0; s < 16; s++) {
      h[s] = exp2f(a2[s] * dt) * h[s] + Bv[s] * u;
      yv += h[s] * Cv[s];
    }
    y[r * INNER + ch] = (bf16)(yv * rsv);
  }
}

// ---------------------------------------------------------------------------
// launch
// ---------------------------------------------------------------------------
extern "C" void kernel_launch(void* const* d_in, const int* in_sizes, int n_in,
                              void* d_out, int out_size, void* d_ws,
                              size_t ws_size, hipStream_t stream) {
  (void)in_sizes; (void)n_in; (void)out_size;
  const float* x      = (const float*)d_in[0];
  const float* w_norm = (const float*)d_in[1];
  const float* W_in   = (const float*)d_in[2];
  const float* conv_w = (const float*)d_in[3];
  const float* conv_b = (const float*)d_in[4];
  const float* W_dt   = (const float*)d_in[5];
  const float* b_dt   = (const float*)d_in[6];
  const float* W_B    = (const float*)d_in[7];
  const float* W_C    = (const float*)d_in[8];
  const float* A_log  = (const float*)d_in[9];
  const float* Dv     = (const float*)d_in[10];
  const float* W_out  = (const float*)d_in[11];
  float* out = (float*)d_out;

  // ---- workspace layout (lifetime-aliased, 173.625 MiB total) -------------
  const size_t MB = 1024ull * 1024ull;
  char* base = (char*)d_ws;
  bf16*  xnorm  = (bf16*)(base + 0);          // 16 MiB [rmsnorm -> gemm1]
  bf16*  win_b  = (bf16*)(base + 16 * MB);    //  8 MiB [pack -> gemm1]
  bf16*  xin_b  = (bf16*)(base + 24 * MB);    // 32 MiB [gemm1 -> conv]
  float* dtm    = (float*)(base + 0);         // 64 MiB [gemm2 -> scan] ALIAS
  float* bcm    = (float*)(base + 64 * MB);   //  1 MiB [bc-gemm -> scan]
  bf16*  res_b  = (bf16*)(base + 65 * MB);    // 32 MiB [gemm1 -> scan]
  bf16*  xc_b   = (bf16*)(base + 97 * MB);    // 32 MiB [conv -> gemm2, scan]
  bf16*  wdt_b  = (bf16*)(base + 129 * MB);   //  8 MiB [pack -> gemm2]
  bf16*  wbc_b  = (bf16*)(base + 137 * MB);   // 0.5 MiB [pack -> bc-gemm]
  // chunk state aliases wdt_b/wbc_b (dead after gemm2/bc):
  float* hend   = (float*)(base + 129 * MB);                 // 8 MiB
  float* dtsum  = (float*)(base + 137 * MB);                 // 0.5 MiB
  char*  p2     = base + 129 * MB + (size_t)NBC * INNER * 2; // = 137.5 MiB
  bf16*  wout_b = (bf16*)p2;                  //  4 MiB [pack -> gemm3]
  float* A2     = (float*)(p2 + (size_t)DIM * INNER * 2);  // 128 KiB
  bf16*  yb     = (bf16*)(p2 + (size_t)DIM * INNER * 2 +
                          (size_t)INNER * STATE * 4);      // 32 MiB [scan->g3]
  const size_t NEEDED = (size_t)((char*)yb - base) + (size_t)ROWS * INNER * 2;

  if (ws_size < NEEDED) {  // diagnostic: fail with absmax == ws_size
    ws_report_kernel<<<1, 64, 0, stream>>>(out, (float)ws_size, (float)NEEDED);
    return;
  }

  // 1. rmsnorm -> xnorm bf16
  rmsnorm_kernel<<<ROWS, 256, 0, stream>>>(x, w_norm, xnorm);

  // 2. weight packs
  cvt_bf16_kernel<<<(N1 * DIM) / 256, 256, 0, stream>>>(W_in, win_b, N1 * DIM);
  cvt_bf16_kernel<<<(INNER * INNER) / 256, 256, 0, stream>>>(W_dt, wdt_b,
                                                             INNER * INNER);
  build_wbc_kernel<<<(128 * INNER) / 256, 256, 0, stream>>>(W_B, W_C, wbc_b);
  cvt_bf16_kernel<<<(DIM * INNER) / 256, 256, 0, stream>>>(W_out, wout_b,
                                                           DIM * INNER);
  build_a2_kernel<<<(INNER * STATE) / 256, 256, 0, stream>>>(A_log, A2);

  // 3. GEMM1: xnorm(8192x1024) @ W_in^T(4096x1024) -> xin_b | silu->res_b
  //    grid 32x16=512 (2 clean generations)
  gemm256_kernel<2, 1024, 16><<<512, 512, 0, stream>>>(
      xnorm, win_b, nullptr, xin_b, res_b, nullptr);

  // 4. conv + silu -> xc_b
  conv_silu_kernel<<<dim3(INNER / 256, ROWS), 256, 0, stream>>>(
      xin_b, conv_w, conv_b, xc_b);

  // 5. GEMM2: xc_b(8192x2048) @ W_dt^T(2048x2048) -> dtm (softplus)
  //    grid 32x8=256 (1 clean generation)
  gemm256_kernel<1, 2048, 8><<<256, 512, 0, stream>>>(
      xc_b, wdt_b, dtm, nullptr, nullptr, b_dt);

  // 5b. bc = xc_b @ [WB;WC]^T -> bcm (8192x32), skinny N=128-pad GEMM
  gemm_bf16_kernel<3><<<64, 256, 0, stream>>>(xc_b, wbc_b, bcm, 1, 128, INNER);

  // 6. chunked scan: pass1 -> combine -> pass3
  scan_pass1_kernel<<<dim3(INNER / 256, NC, BATCH), 256, 0, stream>>>(
      dtm, bcm, xc_b, A2, hend, dtsum);
  scan_combine_kernel<<<(BATCH * 16 * INNER) / 256, 256, 0, stream>>>(
      hend, dtsum, A2);
  scan_pass3_kernel<<<dim3(INNER / 256, NC, BATCH), 256, 0, stream>>>(
      dtm, bcm, xc_b, res_b, A2, Dv, hend, yb);

  // 7. GEMM3: yb(8192x2048) @ W_out^T(1024x2048) -> out f32, grid 32x4=128
  gemm256_kernel<0, 2048, 4><<<128, 512, 0, stream>>>(
      yb, wout_b, out, nullptr, nullptr, nullptr);
}